// Round 21
// baseline (512.672 us; speedup 1.0000x reference)
//
#include <hip/hip_runtime.h>
#include <hip/hip_bf16.h>
#include <stdint.h>

// ---------------------------------------------------------------------------
// CausalSelfAttention with LoRA(Q,K) + RoPE, bf16 MFMA pipeline for gfx950.
// B=4, T=2048, C=2048, H=16, D=128, LORA_R=8.
// r21 = r19 + vT fused into the QKV GEMM epilogue via an LDS transpose
// (fixes r13: stores are now coalesced 16B along t; LDS [d][t] with pad 258
// -> conflict-free writes (bank stride 129 % 32 == 1) and 2-way-free reads).
// k_vt kernel deleted; V panels skip the qkv store.
// Counter-attributed dead ends (do not retry): r13 scattered vT stores;
// r15 no-stage attn; r18 256x128 3-buffer (B-reuse loss, BW-bound);
// r3/r8 launch_bounds min-waves above natural VGPR fit (acc spill);
// paper-refuted: 16-wave 256^2 (VGPR spill), 1-barrier attn (needs 3 bufs).
// ---------------------------------------------------------------------------

typedef __attribute__((ext_vector_type(8))) short short8;
typedef __attribute__((ext_vector_type(4))) short short4v;
typedef __attribute__((ext_vector_type(4))) float floatx4;

// hardware exp2: v_exp_f32 (D = 2^S0)
#define EXP2F(x) __builtin_amdgcn_exp2f(x)

__device__ __forceinline__ float bf2f(short h) {
  union { unsigned int u; float f; } v;
  v.u = ((unsigned int)(unsigned short)h) << 16;
  return v.f;
}
__device__ __forceinline__ short f2bf(float f) {
  unsigned int u = __float_as_uint(f);
  unsigned int r = (u + 0x7FFFu + ((u >> 16) & 1u)) >> 16;  // RNE
  return (short)r;
}
// compiler-native cvt (lets hipcc emit v_cvt_pk_bf16_f32 packing — m240)
__device__ __forceinline__ short f2bf_n(float f) {
  __hip_bfloat16 h = __float2bfloat16(f);
  union { __hip_bfloat16 b; short s; } v; v.b = h; return v.s;
}

__device__ __forceinline__ void gload_lds16(const short* g, short* l) {
  __builtin_amdgcn_global_load_lds(
      (const __attribute__((address_space(1))) unsigned int*)g,
      (__attribute__((address_space(3))) unsigned int*)l, 16, 0, 0);
}

__device__ __forceinline__ void store_out(float* p, float v) { *p = v; }
__device__ __forceinline__ void store_out(short* p, float v) { *p = f2bf(v); }

// bijective XCD swizzle (m204 form; nwg % 8 == 0 for all our grids)
__device__ __forceinline__ int xcd_swz(int orig, int nwg) {
  int q = nwg >> 3;
  return (orig & 7) * q + (orig >> 3);
}

// T2 LDS XOR-swizzle, in SHORT units (flips byte bits 4-6 = short bits 3-5)
#define SWZ(off, row) ((off) ^ (((row) & 7) << 3))

// ---------------- fp32 -> bf16 convert (vectorized) ----------------
__global__ void k_f2b(const float* __restrict__ in, short* __restrict__ out, int n8) {
  int i = blockIdx.x * 256 + threadIdx.x;
  if (i >= n8) return;
  const float4* p = (const float4*)in + (size_t)i * 2;
  float4 a = p[0], b = p[1];
  short8 v;
  v[0] = f2bf(a.x); v[1] = f2bf(a.y); v[2] = f2bf(a.z); v[3] = f2bf(a.w);
  v[4] = f2bf(b.x); v[5] = f2bf(b.y); v[6] = f2bf(b.z); v[7] = f2bf(b.w);
  *(short8*)(out + (size_t)i * 8) = v;
}

// ---------------- W [K][N] fp32 -> WT [N][K] bf16 (tiled transpose) ----------------
__global__ void k_wT(const float* __restrict__ W, short* __restrict__ WT, int K, int N) {
  __shared__ float tile[32][33];
  int n0 = blockIdx.x * 32, k0 = blockIdx.y * 32;
  int tx = threadIdx.x, ty = threadIdx.y;  // (32,8)
  #pragma unroll
  for (int i = 0; i < 4; i++)
    tile[ty + i * 8][tx] = W[(size_t)(k0 + ty + i * 8) * N + n0 + tx];
  __syncthreads();
  #pragma unroll
  for (int i = 0; i < 4; i++)
    WT[(size_t)(n0 + ty + i * 8) * K + k0 + tx] = f2bf(tile[tx][ty + i * 8]);
}

// ---------------- RoPE cos/sin tables [2048][64] fp32 ----------------
__global__ void k_ropetab(float* __restrict__ ct, float* __restrict__ st) {
  int t = blockIdx.x, j = threadIdx.x;  // 64 threads
  float invf = powf(10000.0f, -(float)(2 * j) / 128.0f);
  float ang = (float)t * invf;
  ct[t * 64 + j] = cosf(ang);
  st[t * 64 + j] = sinf(ang);
}

// ---------------- 256x256 8-phase bf16 MFMA GEMM (T2+T3+T4+T5) ----------------
// r10/r12 K-loop (refcheck-proven plateau ~975 TF).  r21 epilogue: V panels
// (QKV launch, bn>=16) transpose through the now-dead 128KB staging LDS
// ([d][t] layout, pad 258 shorts) and store coalesced 16B rows to vT.

#define GBAR __builtin_amdgcn_s_barrier();

#define RDA(QR) \
    _Pragma("unroll") for (int m_ = 0; m_ < 4; m_++) \
    _Pragma("unroll") for (int kk_ = 0; kk_ < 2; kk_++) { \
      int sA_ = ((QR) * 2 + wm) * 8192 + (m_ * 16 + c16) * 128 + kk_ * 64 + g * 16; \
      afr[m_][kk_] = *(const short8*)(Ab + ((sA_ ^ swzk) >> 1)); \
    }

#define RDBX(BB, QC, DST) \
    _Pragma("unroll") for (int n_ = 0; n_ < 2; n_++) \
    _Pragma("unroll") for (int kk_ = 0; kk_ < 2; kk_++) { \
      int sB_ = ((QC) * 4 + wn) * 4096 + (n_ * 16 + c16) * 128 + kk_ * 64 + g * 16; \
      DST[n_][kk_] = *(const short8*)((BB) + ((sB_ ^ swzk) >> 1)); \
    }

#define MM(QR, QC, BF) \
    __builtin_amdgcn_s_barrier(); \
    __builtin_amdgcn_s_setprio(1); \
    _Pragma("unroll") for (int kk_ = 0; kk_ < 2; kk_++) \
    _Pragma("unroll") for (int m_ = 0; m_ < 4; m_++) \
    _Pragma("unroll") for (int n_ = 0; n_ < 2; n_++) \
      acc[(QR) * 4 + m_][(QC) * 2 + n_] = __builtin_amdgcn_mfma_f32_16x16x32_bf16( \
          afr[m_][kk_], BF[n_][kk_], acc[(QR) * 4 + m_][(QC) * 2 + n_], 0, 0, 0); \
    __builtin_amdgcn_s_setprio(0);

template <typename OutT>
__global__ __launch_bounds__(512, 1) void k_gemm8(
    const short* __restrict__ A, const short* __restrict__ BT,
    const float* __restrict__ bias, OutT* __restrict__ C,
    int M, int N, int K, short* __restrict__ vTo)
{
  // 66048 shorts = 129 KB: first 65536 = K-loop staging (layout unchanged);
  // epilogue reuses the whole array as a [256][258] bf16 transpose buffer.
  __shared__ __attribute__((aligned(16))) short lds[66048];
  const int tid = threadIdx.x;
  const int w = tid >> 6, l = tid & 63;
  const int g = l >> 4, c16 = l & 15;
  const int wm = w >> 2, wn = w & 3;
  const int swzk = (c16 & 7) << 4;

  const int nwg = gridDim.x * gridDim.y;
  const int wg = xcd_swz(blockIdx.y * gridDim.x + blockIdx.x, nwg);
  const int bm = wg % gridDim.x, bn = wg / gridDim.x;

  const short* Ablk = A + (size_t)bm * 256 * K;
  const short* Bblk = BT + (size_t)bn * 256 * K;

  floatx4 acc[8][4];
  #pragma unroll
  for (int i = 0; i < 8; i++)
    #pragma unroll
    for (int j = 0; j < 4; j++)
      acc[i][j] = (floatx4){0.f, 0.f, 0.f, 0.f};

  const int NT = K >> 6;   // 64-wide K tiles
  const int L = NT >> 1;   // iterations (2 tiles each)

  // stage one 16KB half of A (2 x 8KB issues): buffer b, half h, K-tile t
  auto stageA = [&](int b, int h, int t) {
    short* dst = lds + b * 32768;
    int k0 = t * 64;
    #pragma unroll
    for (int j = 0; j < 2; j++) {
      int P = h * 2 + j;
      int sL = P * 8192 + tid * 16;                       // linear LDS byte
      int q = sL ^ (((sL >> 7) & 7) << 4);                // inverse-swz source
      int row = (((((P & 1) << 1) | (P >> 1))) << 6) + ((sL >> 7) & 63);
      gload_lds16(Ablk + (size_t)row * K + k0 + ((q & 127) >> 1), dst + (sL >> 1));
    }
  };
  auto stageB = [&](int b, int h, int t) {
    short* dst = lds + b * 32768 + 16384;
    int k0 = t * 64;
    #pragma unroll
    for (int j = 0; j < 2; j++) {
      int sL = (h * 4 + 2 * j) * 4096 + tid * 16;
      int pos = sL >> 12;
      int q = sL ^ (((sL >> 7) & 7) << 4);
      int row = (((pos & 3) * 2 + (pos >> 2)) << 5) + ((sL >> 7) & 31);
      gload_lds16(Bblk + (size_t)row * K + k0 + ((q & 127) >> 1), dst + (sL >> 1));
    }
  };

  // prologue: tile0 -> buf0 (8 issues), tile1 -> buf1 (8 issues)
  stageA(0, 0, 0); stageB(0, 0, 0); stageA(0, 1, 0); stageB(0, 1, 0);
  stageA(1, 0, 1); stageB(1, 0, 1); stageA(1, 1, 1); stageB(1, 1, 1);
  asm volatile("s_waitcnt vmcnt(8)" ::: "memory");  // tile0 landed
  __builtin_amdgcn_s_barrier();

  short8 bfr0[2][2], bfr1[2][2];
  RDBX(lds + 16384, 0, bfr0)   // preload tile0's B0 set

  #pragma unroll 1
  for (int i = 0; i < L; i++) {
    const int t2 = 2 * i + 2, t3 = 2 * i + 3;
    short8 afr[4][2];

    // ---- tile 2i from buf0 (phases 1-4) ----
    {
      const short* Ab = lds;
      RDA(0) if (i > 0) stageA(1, 1, 2 * i + 1);
      MM(0, 0, bfr0) GBAR
      RDBX(lds + 16384, 1, bfr1) if (t2 < NT) stageA(0, 0, t2);
      MM(0, 1, bfr1) GBAR
      RDA(1) if (t2 < NT) stageB(0, 0, t2);
      MM(1, 0, bfr0)
      if (t2 < NT) { asm volatile("s_waitcnt vmcnt(4)" ::: "memory"); }
      else         { asm volatile("s_waitcnt vmcnt(0)" ::: "memory"); }
      GBAR
      RDBX(lds + 49152, 0, bfr0) if (t2 < NT) stageB(0, 1, t2);  // buf1.B0 (early)
      MM(1, 1, bfr1) GBAR
    }
    // ---- tile 2i+1 from buf1 (phases 5-8) ----
    {
      const short* Ab = lds + 32768;
      RDA(0) if (t2 < NT) stageA(0, 1, t2);
      MM(0, 0, bfr0) GBAR
      RDBX(lds + 49152, 1, bfr1) if (t3 < NT) stageA(1, 0, t3);
      MM(0, 1, bfr1) GBAR
      RDA(1) if (t3 < NT) stageB(1, 0, t3);
      MM(1, 0, bfr0)
      if (t3 < NT) { asm volatile("s_waitcnt vmcnt(4)" ::: "memory"); }
      else         { asm volatile("s_waitcnt vmcnt(0)" ::: "memory"); }
      GBAR
      if (t2 < NT) { RDBX(lds + 16384, 0, bfr0) }  // next buf0.B0 (early)
      if (t3 < NT) stageB(1, 1, t3);
      MM(1, 1, bfr1) GBAR
    }
  }
  // loop's final vmcnt(0)+GBAR: all staging done, all LDS reads done.

  if (vTo && bn >= 16) {
    // ---- V-panel epilogue: transpose via LDS, coalesced stores to vT ----
    // write acc (bf16) to lds[d_local*258 + t_local]: lanes step d by 1 ->
    // bank stride 129 % 32 == 1 -> conflict-free scalar writes.
    #pragma unroll
    for (int qr = 0; qr < 2; qr++)
      #pragma unroll
      for (int qc = 0; qc < 2; qc++)
        #pragma unroll
        for (int m = 0; m < 4; m++)
          #pragma unroll
          for (int n = 0; n < 2; n++) {
            int dl = wn * 64 + qc * 32 + n * 16 + c16;
            float bv = bias[bn * 256 + dl];
            #pragma unroll
            for (int r = 0; r < 4; r++) {
              int tl = wm * 128 + qr * 64 + m * 16 + g * 4 + r;
              lds[dl * 258 + tl] = f2bf_n(acc[qr * 4 + m][qc * 2 + n][r] + bv);
            }
          }
    __syncthreads();
    // readout: thread -> d_local = tid>>1, t-half = (tid&1)*128;
    // reads along t are contiguous (2-way lane aliasing = free);
    // stores are 16B coalesced along t.
    const int dl = tid >> 1, th = (tid & 1) * 128;
    const int col = bn * 256 + dl;                 // global v-dim col (>=4096)
    const int hh = (col - 4096) >> 7, dd = col & 127;
    const int bb = bm >> 3, tt0 = (bm & 7) * 256 + th;
    short* dst = vTo + ((size_t)((bb * 16 + hh) * 128 + dd)) * 2048 + tt0;
    const short* src = lds + dl * 258 + th;
    #pragma unroll
    for (int i2 = 0; i2 < 16; i2++)
      *(short8*)(dst + i2 * 8) = *(const short8*)(src + i2 * 8);
    return;
  }

  // epilogue: acc -> C (+bias)
  #pragma unroll
  for (int qr = 0; qr < 2; qr++)
    #pragma unroll
    for (int qc = 0; qc < 2; qc++)
      #pragma unroll
      for (int m = 0; m < 4; m++)
        #pragma unroll
        for (int n = 0; n < 2; n++) {
          int col = bn * 256 + wn * 64 + qc * 32 + n * 16 + c16;
          float bv = bias[col];
          #pragma unroll
          for (int r = 0; r < 4; r++) {
            size_t row = (size_t)bm * 256 + wm * 128 + qr * 64 + m * 16 + g * 4 + r;
            store_out(C + row * (size_t)N + col, acc[qr * 4 + m][qc * 2 + n][r] + bv);
          }
        }
}

// ---------------- fused LoRA (T = row@A; delta = T@B) + RoPE, in-place ----------------
// q-scale folds log2(e): 1/sqrt(128) * log2(e) = 0.127517403.
__global__ __launch_bounds__(256, 2) void k_lorarope(
    short* __restrict__ qkv, const float* __restrict__ Aq, const float* __restrict__ Ak,
    const float* __restrict__ Bq, const float* __restrict__ Bk,
    const float* __restrict__ ct, const float* __restrict__ st)
{
  __shared__ float Bs[8 * 2048];   // 64 KB
  __shared__ short Ls[2048];       // row cache (bf16)
  __shared__ float red[4][8];
  const int u = threadIdx.x;
  const int which = blockIdx.y;
  const float* Am = which ? Ak : Aq;
  const float* Bm = which ? Bk : Bq;
  const float qs = which ? 1.0f : 0.127517403f;  // (1/sqrt(128))*log2e on q

  #pragma unroll
  for (int i = 0; i < 16; i++) {
    int idx = (i * 256 + u) * 4;
    *(float4*)(Bs + idx) = *(const float4*)(Bm + idx);
  }
  float Areg[8][8];
  #pragma unroll
  for (int e = 0; e < 8; e++) {
    float4 a0 = *(const float4*)(Am + (size_t)(u * 8 + e) * 8);
    float4 a1 = *(const float4*)(Am + (size_t)(u * 8 + e) * 8 + 4);
    Areg[e][0] = a0.x; Areg[e][1] = a0.y; Areg[e][2] = a0.z; Areg[e][3] = a0.w;
    Areg[e][4] = a1.x; Areg[e][5] = a1.y; Areg[e][6] = a1.z; Areg[e][7] = a1.w;
  }
  __syncthreads();

  const int wv = u >> 6, l = u & 63;
  const int h = u >> 4, j0 = (u & 15) * 4;
  const int base = h * 128;
  const int t0 = blockIdx.x * 16;

  for (int tt = 0; tt < 16; tt++) {
    const int tok = t0 + tt;
    const int trow = tok & 2047;
    short* row = qkv + (size_t)tok * 6144 + which * 2048;

    __syncthreads();  // prior iter's Ls reads done before overwrite

    short8 q8 = *(const short8*)(row + u * 8);
    *(short8*)(Ls + u * 8) = q8;
    float part[8];
    #pragma unroll
    for (int r = 0; r < 8; r++) part[r] = 0.f;
    #pragma unroll
    for (int e = 0; e < 8; e++) {
      float qv = bf2f(q8[e]);
      #pragma unroll
      for (int r = 0; r < 8; r++) part[r] += qv * Areg[e][r];
    }
    #pragma unroll
    for (int r = 0; r < 8; r++)
      for (int off = 32; off > 0; off >>= 1)
        part[r] += __shfl_xor(part[r], off);
    if (l == 0) {
      #pragma unroll
      for (int r = 0; r < 8; r++) red[wv][r] = part[r];
    }
    __syncthreads();  // T ready; also: Ls visible to all

    float Tr[8];
    #pragma unroll
    for (int r = 0; r < 8; r++)
      Tr[r] = (red[0][r] + red[1][r] + red[2][r] + red[3][r]) * 0.125f;  // LORA_SCALING

    float4 cv = *(const float4*)(ct + trow * 64 + j0);
    float4 sv = *(const float4*)(st + trow * 64 + j0);
    short4v qa4 = *(const short4v*)(Ls + base + j0);
    short4v qb4 = *(const short4v*)(Ls + base + 64 + j0);
    short8 qeo = *(const short8*)(Ls + base + 2 * j0);

    float o1[4], o2[4];
    #pragma unroll
    for (int j = 0; j < 4; j++) {
      float da = 0.f, db = 0.f, de = 0.f, dd = 0.f;
      #pragma unroll
      for (int r = 0; r < 8; r++) {
        const float* Br = Bs + r * 2048 + base;
        da += Tr[r] * Br[j0 + j];
        db += Tr[r] * Br[64 + j0 + j];
        de += Tr[r] * Br[2 * (j0 + j)];
        dd += Tr[r] * Br[2 * (j0 + j) + 1];
      }
      float qa = bf2f(qa4[j]) + da;
      float qb = bf2f(qb4[j]) + db;
      float qe = bf2f(qeo[2 * j]) + de;
      float qo = bf2f(qeo[2 * j + 1]) + dd;
      float c = ((const float*)&cv)[j], s = ((const float*)&sv)[j];
      o1[j] = (qa * c - qo * s) * qs;
      o2[j] = (qb * c + qe * s) * qs;
    }
    short4v w1, w2;
    #pragma unroll
    for (int j = 0; j < 4; j++) { w1[j] = f2bf(o1[j]); w2[j] = f2bf(o2[j]); }
    *(short4v*)(row + base + j0) = w1;        // safe: global reads were pass-1 only
    *(short4v*)(row + base + 64 + j0) = w2;
  }
}

// ---------------- causal flash attention v8 (r12/r14/r17 proven) ----------------
// 40KB swizzled LDS; P-region 2KB/wave with two m-passes; lane-local
// defer-max; exp2 softmax; MFMA-ones row-sum.  launch_bounds(256,2) ONLY.
// K/V LDS staging REQUIRED (r15).
__global__ __launch_bounds__(256, 2) void k_attn(
    const short* __restrict__ qkv, const short* __restrict__ vT, short* __restrict__ y)
{
  __shared__ __attribute__((aligned(16))) short Ks[64 * 128];     // 16 KB, swz
  __shared__ __attribute__((aligned(16))) short Vs[128 * 64];     // 16 KB, swz
  __shared__ __attribute__((aligned(16))) short Ps[4 * 16 * 64];  // 8 KB, swz
  const int bh = blockIdx.x, b = bh >> 4, h = bh & 15;
  const int qt = 15 - (int)blockIdx.y;
  const int t = threadIdx.x, w = t >> 6, l = t & 63, g = l >> 4, c16 = l & 15;

  const int skr = t >> 2, sc0 = (t & 3) * 32;   // K staging: row, col base
  const int svd = t >> 1, sv0 = (t & 1) * 32;   // V staging
  const short* kbase = qkv + (size_t)(b * 2048) * 6144 + 2048 + h * 128;
  const short* vbase = vT + (size_t)bh * 128 * 2048;
  short* Pw = Ps + w * (16 * 64);

  short8 onesv;
  #pragma unroll
  for (int e = 0; e < 8; e++) onesv[e] = (short)0x3F80;  // bf16 1.0

  // Q A-fragments: wave w rows qt*128 + w*32 + m*16 + c16
  short8 qf[2][4];
  #pragma unroll
  for (int m = 0; m < 2; m++) {
    size_t goff = (size_t)(b * 2048 + qt * 128 + w * 32 + m * 16 + c16) * 6144 + h * 128;
    #pragma unroll
    for (int kf = 0; kf < 4; kf++)
      qf[m][kf] = *(const short8*)(qkv + goff + kf * 32 + 8 * g);
  }

  floatx4 o[2][8], ls[2];
  float mrow[2][4];
  #pragma unroll
  for (int m = 0; m < 2; m++) {
    #pragma unroll
    for (int nf = 0; nf < 8; nf++) o[m][nf] = (floatx4){0.f, 0.f, 0.f, 0.f};
    ls[m] = (floatx4){0.f, 0.f, 0.f, 0.f};
    #pragma unroll
    for (int r = 0; r < 4; r++) mrow[m][r] = -1e30f;
  }

  const int ntiles = 2 * qt + 2;

  // prologue: issue tile-0 loads into regs
  short8 kreg[4], vreg[4];
  #pragma unroll
  for (int ii = 0; ii < 4; ii++) {
    kreg[ii] = *(const short8*)(kbase + (size_t)skr * 6144 + sc0 + ii * 8);
    vreg[ii] = *(const short8*)(vbase + (size_t)svd * 2048 + sv0 + ii * 8);
  }

  for (int kt = 0; kt < ntiles; kt++) {
    __syncthreads();  // prior iter's LDS reads complete before overwrite
    #pragma unroll
    for (int ii = 0; ii < 4; ii++) {
      *(short8*)(Ks + SWZ(skr * 128 + sc0 + ii * 8, skr)) = kreg[ii];
      *(short8*)(Vs + SWZ(svd * 64 + sv0 + ii * 8, svd)) = vreg[ii];
    }
    __syncthreads();  // staged tile visible

    // T14: issue NEXT tile's global loads now; latency hides under compute.
    if (kt + 1 < ntiles) {
      #pragma unroll
      for (int ii = 0; ii < 4; ii++) {
        kreg[ii] = *(const short8*)(kbase + (size_t)((kt + 1) * 64 + skr) * 6144 + sc0 + ii * 8);
        vreg[ii] = *(const short8*)(vbase + (size_t)svd * 2048 + (kt + 1) * 64 + sv0 + ii * 8);
      }
    }

    // ---- QK^T: sc[m][nf] over 64 keys (scores already in log2 units) ----
    floatx4 sc[2][4];
    #pragma unroll
    for (int m = 0; m < 2; m++)
      #pragma unroll
      for (int nf = 0; nf < 4; nf++) sc[m][nf] = (floatx4){0.f, 0.f, 0.f, 0.f};
    __builtin_amdgcn_s_setprio(1);
    #pragma unroll
    for (int kf = 0; kf < 4; kf++)
      #pragma unroll
      for (int nf = 0; nf < 4; nf++) {
        short8 kb = *(const short8*)(Ks + SWZ((nf * 16 + c16) * 128 + kf * 32 + 8 * g, c16));
        sc[0][nf] = __builtin_amdgcn_mfma_f32_16x16x32_bf16(qf[0][kf], kb, sc[0][nf], 0, 0, 0);
        sc[1][nf] = __builtin_amdgcn_mfma_f32_16x16x32_bf16(qf[1][kf], kb, sc[1][nf], 0, 0, 0);
      }
    __builtin_amdgcn_s_setprio(0);

    if (kt >= 2 * qt) {  // diagonal region: causal mask
      #pragma unroll
      for (int m = 0; m < 2; m++)
        #pragma unroll
        for (int nf = 0; nf < 4; nf++) {
          int key = kt * 64 + nf * 16 + c16;
          #pragma unroll
          for (int r = 0; r < 4; r++) {
            int qr = qt * 128 + w * 32 + m * 16 + g * 4 + r;
            if (key > qr) sc[m][nf][r] = -1e30f;
          }
        }
    }

    // ---- defer-max check: LANE-LOCAL (no cross-lane tree in common path) ----
    float need = -1e30f;
    #pragma unroll
    for (int m = 0; m < 2; m++)
      #pragma unroll
      for (int r = 0; r < 4; r++) {
        float rm = fmaxf(fmaxf(sc[m][0][r], sc[m][1][r]), fmaxf(sc[m][2][r], sc[m][3][r]));
        need = fmaxf(need, rm - mrow[m][r]);
      }
    if (!__all(need <= 11.0f)) {  // rare: full row-max tree + rescale
      #pragma unroll
      for (int m = 0; m < 2; m++) {
        #pragma unroll
        for (int r = 0; r < 4; r++) {
          float rm = fmaxf(fmaxf(sc[m][0][r], sc[m][1][r]), fmaxf(sc[m][2][r], sc[m][3][r]));
          rm = fmaxf(rm, __shfl_xor(rm, 1));
          rm = fmaxf(rm, __shfl_xor(rm, 2));
          rm = fmaxf(rm, __shfl_xor(rm, 4));
          rm = fmaxf(rm, __shfl_xor(rm, 8));
          float mn = fmaxf(mrow[m][r], rm);
          float al = EXP2F(mrow[m][r] - mn);
          mrow[m][r] = mn;
          ls[m][r] *= al;
          #pragma unroll
          for (int nf = 0; nf < 8; nf++) o[m][nf][r] *= al;
        }
      }
    }

    // ---- P + PV, two m-passes over the wave-private 2KB P region ----
    short8 pa[2][2];
    #pragma unroll
    for (int m = 0; m < 2; m++) {
      #pragma unroll
      for (int r = 0; r < 4; r++) {
        int prow = g * 4 + r;
        #pragma unroll
        for (int nf = 0; nf < 4; nf++) {
          float p = EXP2F(sc[m][nf][r] - mrow[m][r]);
          Pw[SWZ(prow * 64 + nf * 16 + c16, prow)] = f2bf_n(p);
        }
      }
      #pragma unroll
      for (int kf = 0; kf < 2; kf++)
        pa[m][kf] = *(const short8*)(Pw + SWZ(c16 * 64 + kf * 32 + 8 * g, c16));
      if (m == 0) {  // pa[0] data must be in regs before m=1 overwrites the region
        asm volatile("s_waitcnt lgkmcnt(0)" ::: "memory");
        __builtin_amdgcn_sched_barrier(0);
      }
    }
    __builtin_amdgcn_s_setprio(1);
    #pragma unroll
    for (int m = 0; m < 2; m++)
      #pragma unroll
      for (int kf = 0; kf < 2; kf++)
        ls[m] = __builtin_amdgcn_mfma_f32_16x16x32_bf16(pa[m][kf], onesv, ls[m], 0, 0, 0);
    #pragma unroll
    for (int kf = 0; kf < 2; kf++)
      #pragma unroll
      for (int nf = 0; nf < 8; nf++) {
        short8 vb = *(const short8*)(Vs + SWZ((nf * 16 + c16) * 64 + kf * 32 + 8 * g, c16));
        o[0][nf] = __builtin_amdgcn_mfma_f32_16x16x32_bf16(pa[0][kf], vb, o[0][nf], 0, 0, 0);
        o[1][nf] = __builtin_amdgcn_mfma_f32_16x16x32_bf16(pa[1][kf], vb, o[1][nf], 0, 0, 0);
      }
    __builtin_amdgcn_s_setprio(0);
  }

  #pragma unroll
  for (int m = 0; m < 2; m++) {
    float ri[4];
    #pragma unroll
    for (int r = 0; r < 4; r++) ri[r] = 1.0f / ls[m][r];
    size_t yr0 = (size_t)(b * 2048 + qt * 128 + w * 32 + m * 16 + g * 4);
    #pragma unroll
    for (int nf = 0; nf < 8; nf++) {
      int col = h * 128 + nf * 16 + c16;
      #pragma unroll
      for (int r = 0; r < 4; r++)
        y[(yr0 + r) * 2048 + col] = f2bf_n(o[m][nf][r] * ri[r]);
    }
  }
}

// ---------------------------------------------------------------------------
extern "C" void kernel_launch(void* const* d_in, const int* in_sizes, int n_in,
                              void* d_out, int out_size, void* d_ws, size_t ws_size,
                              hipStream_t stream) {
  (void)in_sizes; (void)n_in; (void)out_size; (void)ws_size;
  const float* x      = (const float*)d_in[0];
  const float* W_attn = (const float*)d_in[1];
  const float* b_attn = (const float*)d_in[2];
  const float* Aq     = (const float*)d_in[3];
  const float* Bq     = (const float*)d_in[4];
  const float* Ak     = (const float*)d_in[5];
  const float* Bk     = (const float*)d_in[6];
  const float* W_proj = (const float*)d_in[7];
  const float* b_proj = (const float*)d_in[8];

  char* ws = (char*)d_ws;
  short* xb  = (short*)(ws + 0);          // 8192x2048 bf16 (reused as y)
  short* WTa = (short*)(ws + 33554432);   // 6144x2048 bf16
  short* WTp = (short*)(ws + 58720256);   // 2048x2048 bf16
  short* qkv = (short*)(ws + 67108864);   // 8192x6144 bf16 (v-slice unused now)
  float* ct  = (float*)(ws + 168296448);  // 2048x64 f32
  float* st  = (float*)(ws + 168820736);
  short* vT  = (short*)(ws + 169345024);  // 64x128x2048 bf16  (end: 202899456)
  short* y   = xb;

  k_f2b<<<8192, 256, 0, stream>>>(x, xb, 2097152);
  k_wT<<<dim3(192, 64), dim3(32, 8), 0, stream>>>(W_attn, WTa, 2048, 6144);
  k_wT<<<dim3(64, 64), dim3(32, 8), 0, stream>>>(W_proj, WTp, 2048, 2048);
  k_ropetab<<<2048, 64, 0, stream>>>(ct, st);
  k_gemm8<short><<<dim3(32, 24), 512, 0, stream>>>(xb, WTa, b_attn, qkv, 8192, 6144, 2048, vT);
  k_lorarope<<<dim3(512, 2), 256, 0, stream>>>(qkv, Aq, Ak, Bq, Bk, ct, st);
  k_attn<<<dim3(64, 16), 256, 0, stream>>>(qkv, vT, y);
  k_gemm8<float><<<dim3(32, 8), 512, 0, stream>>>(y, WTp, b_proj, (float*)d_out, 8192, 2048, 2048, nullptr);
}

// Round 22
// 506.886 us; speedup vs baseline: 1.0114x; 1.0114x over previous
//
#include <hip/hip_runtime.h>
#include <hip/hip_bf16.h>
#include <stdint.h>

// ---------------------------------------------------------------------------
// CausalSelfAttention with LoRA(Q,K) + RoPE, bf16 MFMA pipeline for gfx950.
// B=4, T=2048, C=2048, H=16, D=128, LORA_R=8.
// r22 = r19 config (best measured 510.5us) + attn diagonal wave-skip
// (waves 0-1 skip the fully-masked last kv-tile: P==0 there, contributes
// nothing; compute section holds no block barrier so the skip is wave-local).
// Counter-attributed dead ends (do not retry):
//   r13 scattered vT stores (WRITE 122->232MB); r21 LDS-transposed vT fusion
//   (neutral: +17us QKV = -15us k_vt); r15 no-stage attn (+95us);
//   r18 256x128 3-buffer (B-reuse loss -> BW-bound); r3/r8 launch_bounds
//   min-waves above natural VGPR fit (acc spill to scratch).
// ---------------------------------------------------------------------------

typedef __attribute__((ext_vector_type(8))) short short8;
typedef __attribute__((ext_vector_type(4))) short short4v;
typedef __attribute__((ext_vector_type(4))) float floatx4;

// hardware exp2: v_exp_f32 (D = 2^S0)
#define EXP2F(x) __builtin_amdgcn_exp2f(x)

__device__ __forceinline__ float bf2f(short h) {
  union { unsigned int u; float f; } v;
  v.u = ((unsigned int)(unsigned short)h) << 16;
  return v.f;
}
__device__ __forceinline__ short f2bf(float f) {
  unsigned int u = __float_as_uint(f);
  unsigned int r = (u + 0x7FFFu + ((u >> 16) & 1u)) >> 16;  // RNE
  return (short)r;
}
// compiler-native cvt (lets hipcc emit v_cvt_pk_bf16_f32 packing — m240)
__device__ __forceinline__ short f2bf_n(float f) {
  __hip_bfloat16 h = __float2bfloat16(f);
  union { __hip_bfloat16 b; short s; } v; v.b = h; return v.s;
}

__device__ __forceinline__ void gload_lds16(const short* g, short* l) {
  __builtin_amdgcn_global_load_lds(
      (const __attribute__((address_space(1))) unsigned int*)g,
      (__attribute__((address_space(3))) unsigned int*)l, 16, 0, 0);
}

__device__ __forceinline__ void store_out(float* p, float v) { *p = v; }
__device__ __forceinline__ void store_out(short* p, float v) { *p = f2bf(v); }

// bijective XCD swizzle (m204 form; nwg % 8 == 0 for all our grids)
__device__ __forceinline__ int xcd_swz(int orig, int nwg) {
  int q = nwg >> 3;
  return (orig & 7) * q + (orig >> 3);
}

// T2 LDS XOR-swizzle, in SHORT units (flips byte bits 4-6 = short bits 3-5)
#define SWZ(off, row) ((off) ^ (((row) & 7) << 3))

// ---------------- fp32 -> bf16 convert (vectorized) ----------------
__global__ void k_f2b(const float* __restrict__ in, short* __restrict__ out, int n8) {
  int i = blockIdx.x * 256 + threadIdx.x;
  if (i >= n8) return;
  const float4* p = (const float4*)in + (size_t)i * 2;
  float4 a = p[0], b = p[1];
  short8 v;
  v[0] = f2bf(a.x); v[1] = f2bf(a.y); v[2] = f2bf(a.z); v[3] = f2bf(a.w);
  v[4] = f2bf(b.x); v[5] = f2bf(b.y); v[6] = f2bf(b.z); v[7] = f2bf(b.w);
  *(short8*)(out + (size_t)i * 8) = v;
}

// ---------------- W [K][N] fp32 -> WT [N][K] bf16 (tiled transpose) ----------------
__global__ void k_wT(const float* __restrict__ W, short* __restrict__ WT, int K, int N) {
  __shared__ float tile[32][33];
  int n0 = blockIdx.x * 32, k0 = blockIdx.y * 32;
  int tx = threadIdx.x, ty = threadIdx.y;  // (32,8)
  #pragma unroll
  for (int i = 0; i < 4; i++)
    tile[ty + i * 8][tx] = W[(size_t)(k0 + ty + i * 8) * N + n0 + tx];
  __syncthreads();
  #pragma unroll
  for (int i = 0; i < 4; i++)
    WT[(size_t)(n0 + ty + i * 8) * K + k0 + tx] = f2bf(tile[tx][ty + i * 8]);
}

// ---------------- RoPE cos/sin tables [2048][64] fp32 ----------------
__global__ void k_ropetab(float* __restrict__ ct, float* __restrict__ st) {
  int t = blockIdx.x, j = threadIdx.x;  // 64 threads
  float invf = powf(10000.0f, -(float)(2 * j) / 128.0f);
  float ang = (float)t * invf;
  ct[t * 64 + j] = cosf(ang);
  st[t * 64 + j] = sinf(ang);
}

// ---------------- 256x256 8-phase bf16 MFMA GEMM (T2+T3+T4+T5) ----------------
// r10/r12 structure: balanced phases (8/4/8/4 reads), fragment reuse, one
// staged half + counted vmcnt(4)/phase.  Refcheck-proven plateau (~968 TF).

#define GBAR __builtin_amdgcn_s_barrier();

#define RDA(QR) \
    _Pragma("unroll") for (int m_ = 0; m_ < 4; m_++) \
    _Pragma("unroll") for (int kk_ = 0; kk_ < 2; kk_++) { \
      int sA_ = ((QR) * 2 + wm) * 8192 + (m_ * 16 + c16) * 128 + kk_ * 64 + g * 16; \
      afr[m_][kk_] = *(const short8*)(Ab + ((sA_ ^ swzk) >> 1)); \
    }

#define RDBX(BB, QC, DST) \
    _Pragma("unroll") for (int n_ = 0; n_ < 2; n_++) \
    _Pragma("unroll") for (int kk_ = 0; kk_ < 2; kk_++) { \
      int sB_ = ((QC) * 4 + wn) * 4096 + (n_ * 16 + c16) * 128 + kk_ * 64 + g * 16; \
      DST[n_][kk_] = *(const short8*)((BB) + ((sB_ ^ swzk) >> 1)); \
    }

#define MM(QR, QC, BF) \
    __builtin_amdgcn_s_barrier(); \
    __builtin_amdgcn_s_setprio(1); \
    _Pragma("unroll") for (int kk_ = 0; kk_ < 2; kk_++) \
    _Pragma("unroll") for (int m_ = 0; m_ < 4; m_++) \
    _Pragma("unroll") for (int n_ = 0; n_ < 2; n_++) \
      acc[(QR) * 4 + m_][(QC) * 2 + n_] = __builtin_amdgcn_mfma_f32_16x16x32_bf16( \
          afr[m_][kk_], BF[n_][kk_], acc[(QR) * 4 + m_][(QC) * 2 + n_], 0, 0, 0); \
    __builtin_amdgcn_s_setprio(0);

template <typename OutT>
__global__ __launch_bounds__(512, 2) void k_gemm8(
    const short* __restrict__ A, const short* __restrict__ BT,
    const float* __restrict__ bias, OutT* __restrict__ C,
    int M, int N, int K)
{
  __shared__ __attribute__((aligned(16))) short lds[65536];  // 128 KB
  const int tid = threadIdx.x;
  const int w = tid >> 6, l = tid & 63;
  const int g = l >> 4, c16 = l & 15;
  const int wm = w >> 2, wn = w & 3;
  const int swzk = (c16 & 7) << 4;

  const int nwg = gridDim.x * gridDim.y;
  const int wg = xcd_swz(blockIdx.y * gridDim.x + blockIdx.x, nwg);
  const int bm = wg % gridDim.x, bn = wg / gridDim.x;

  const short* Ablk = A + (size_t)bm * 256 * K;
  const short* Bblk = BT + (size_t)bn * 256 * K;

  floatx4 acc[8][4];
  #pragma unroll
  for (int i = 0; i < 8; i++)
    #pragma unroll
    for (int j = 0; j < 4; j++)
      acc[i][j] = (floatx4){0.f, 0.f, 0.f, 0.f};

  const int NT = K >> 6;   // 64-wide K tiles
  const int L = NT >> 1;   // iterations (2 tiles each)

  // stage one 16KB half of A (2 x 8KB issues): buffer b, half h, K-tile t
  auto stageA = [&](int b, int h, int t) {
    short* dst = lds + b * 32768;
    int k0 = t * 64;
    #pragma unroll
    for (int j = 0; j < 2; j++) {
      int P = h * 2 + j;
      int sL = P * 8192 + tid * 16;                       // linear LDS byte
      int q = sL ^ (((sL >> 7) & 7) << 4);                // inverse-swz source
      int row = (((((P & 1) << 1) | (P >> 1))) << 6) + ((sL >> 7) & 63);
      gload_lds16(Ablk + (size_t)row * K + k0 + ((q & 127) >> 1), dst + (sL >> 1));
    }
  };
  auto stageB = [&](int b, int h, int t) {
    short* dst = lds + b * 32768 + 16384;
    int k0 = t * 64;
    #pragma unroll
    for (int j = 0; j < 2; j++) {
      int sL = (h * 4 + 2 * j) * 4096 + tid * 16;
      int pos = sL >> 12;
      int q = sL ^ (((sL >> 7) & 7) << 4);
      int row = (((pos & 3) * 2 + (pos >> 2)) << 5) + ((sL >> 7) & 31);
      gload_lds16(Bblk + (size_t)row * K + k0 + ((q & 127) >> 1), dst + (sL >> 1));
    }
  };

  // prologue: tile0 -> buf0 (8 issues), tile1 -> buf1 (8 issues)
  stageA(0, 0, 0); stageB(0, 0, 0); stageA(0, 1, 0); stageB(0, 1, 0);
  stageA(1, 0, 1); stageB(1, 0, 1); stageA(1, 1, 1); stageB(1, 1, 1);
  asm volatile("s_waitcnt vmcnt(8)" ::: "memory");  // tile0 landed
  __builtin_amdgcn_s_barrier();

  short8 bfr0[2][2], bfr1[2][2];
  RDBX(lds + 16384, 0, bfr0)   // preload tile0's B0 set

  #pragma unroll 1
  for (int i = 0; i < L; i++) {
    const int t2 = 2 * i + 2, t3 = 2 * i + 3;
    short8 afr[4][2];

    // ---- tile 2i from buf0 (phases 1-4) ----
    {
      const short* Ab = lds;
      RDA(0) if (i > 0) stageA(1, 1, 2 * i + 1);
      MM(0, 0, bfr0) GBAR
      RDBX(lds + 16384, 1, bfr1) if (t2 < NT) stageA(0, 0, t2);
      MM(0, 1, bfr1) GBAR
      RDA(1) if (t2 < NT) stageB(0, 0, t2);
      MM(1, 0, bfr0)
      if (t2 < NT) { asm volatile("s_waitcnt vmcnt(4)" ::: "memory"); }
      else         { asm volatile("s_waitcnt vmcnt(0)" ::: "memory"); }
      GBAR
      RDBX(lds + 49152, 0, bfr0) if (t2 < NT) stageB(0, 1, t2);  // buf1.B0 (early)
      MM(1, 1, bfr1) GBAR
    }
    // ---- tile 2i+1 from buf1 (phases 5-8) ----
    {
      const short* Ab = lds + 32768;
      RDA(0) if (t2 < NT) stageA(0, 1, t2);
      MM(0, 0, bfr0) GBAR
      RDBX(lds + 49152, 1, bfr1) if (t3 < NT) stageA(1, 0, t3);
      MM(0, 1, bfr1) GBAR
      RDA(1) if (t3 < NT) stageB(1, 0, t3);
      MM(1, 0, bfr0)
      if (t3 < NT) { asm volatile("s_waitcnt vmcnt(4)" ::: "memory"); }
      else         { asm volatile("s_waitcnt vmcnt(0)" ::: "memory"); }
      GBAR
      if (t2 < NT) { RDBX(lds + 16384, 0, bfr0) }  // next buf0.B0 (early)
      if (t3 < NT) stageB(1, 1, t3);
      MM(1, 1, bfr1) GBAR
    }
  }

  // epilogue: acc -> C (+bias)
  #pragma unroll
  for (int qr = 0; qr < 2; qr++)
    #pragma unroll
    for (int qc = 0; qc < 2; qc++)
      #pragma unroll
      for (int m = 0; m < 4; m++)
        #pragma unroll
        for (int n = 0; n < 2; n++) {
          int col = bn * 256 + wn * 64 + qc * 32 + n * 16 + c16;
          float bv = bias[col];
          #pragma unroll
          for (int r = 0; r < 4; r++) {
            size_t row = (size_t)bm * 256 + wm * 128 + qr * 64 + m * 16 + g * 4 + r;
            store_out(C + row * (size_t)N + col, acc[qr * 4 + m][qc * 2 + n][r] + bv);
          }
        }
}

// ---------------- fused LoRA (T = row@A; delta = T@B) + RoPE, in-place ----------------
// q-scale folds log2(e): 1/sqrt(128) * log2(e) = 0.127517403.
__global__ __launch_bounds__(256, 2) void k_lorarope(
    short* __restrict__ qkv, const float* __restrict__ Aq, const float* __restrict__ Ak,
    const float* __restrict__ Bq, const float* __restrict__ Bk,
    const float* __restrict__ ct, const float* __restrict__ st)
{
  __shared__ float Bs[8 * 2048];   // 64 KB
  __shared__ short Ls[2048];       // row cache (bf16)
  __shared__ float red[4][8];
  const int u = threadIdx.x;
  const int which = blockIdx.y;
  const float* Am = which ? Ak : Aq;
  const float* Bm = which ? Bk : Bq;
  const float qs = which ? 1.0f : 0.127517403f;  // (1/sqrt(128))*log2e on q

  #pragma unroll
  for (int i = 0; i < 16; i++) {
    int idx = (i * 256 + u) * 4;
    *(float4*)(Bs + idx) = *(const float4*)(Bm + idx);
  }
  float Areg[8][8];
  #pragma unroll
  for (int e = 0; e < 8; e++) {
    float4 a0 = *(const float4*)(Am + (size_t)(u * 8 + e) * 8);
    float4 a1 = *(const float4*)(Am + (size_t)(u * 8 + e) * 8 + 4);
    Areg[e][0] = a0.x; Areg[e][1] = a0.y; Areg[e][2] = a0.z; Areg[e][3] = a0.w;
    Areg[e][4] = a1.x; Areg[e][5] = a1.y; Areg[e][6] = a1.z; Areg[e][7] = a1.w;
  }
  __syncthreads();

  const int wv = u >> 6, l = u & 63;
  const int h = u >> 4, j0 = (u & 15) * 4;
  const int base = h * 128;
  const int t0 = blockIdx.x * 16;

  for (int tt = 0; tt < 16; tt++) {
    const int tok = t0 + tt;
    const int trow = tok & 2047;
    short* row = qkv + (size_t)tok * 6144 + which * 2048;

    __syncthreads();  // prior iter's Ls reads done before overwrite

    short8 q8 = *(const short8*)(row + u * 8);
    *(short8*)(Ls + u * 8) = q8;
    float part[8];
    #pragma unroll
    for (int r = 0; r < 8; r++) part[r] = 0.f;
    #pragma unroll
    for (int e = 0; e < 8; e++) {
      float qv = bf2f(q8[e]);
      #pragma unroll
      for (int r = 0; r < 8; r++) part[r] += qv * Areg[e][r];
    }
    #pragma unroll
    for (int r = 0; r < 8; r++)
      for (int off = 32; off > 0; off >>= 1)
        part[r] += __shfl_xor(part[r], off);
    if (l == 0) {
      #pragma unroll
      for (int r = 0; r < 8; r++) red[wv][r] = part[r];
    }
    __syncthreads();  // T ready; also: Ls visible to all

    float Tr[8];
    #pragma unroll
    for (int r = 0; r < 8; r++)
      Tr[r] = (red[0][r] + red[1][r] + red[2][r] + red[3][r]) * 0.125f;  // LORA_SCALING

    float4 cv = *(const float4*)(ct + trow * 64 + j0);
    float4 sv = *(const float4*)(st + trow * 64 + j0);
    short4v qa4 = *(const short4v*)(Ls + base + j0);
    short4v qb4 = *(const short4v*)(Ls + base + 64 + j0);
    short8 qeo = *(const short8*)(Ls + base + 2 * j0);

    float o1[4], o2[4];
    #pragma unroll
    for (int j = 0; j < 4; j++) {
      float da = 0.f, db = 0.f, de = 0.f, dd = 0.f;
      #pragma unroll
      for (int r = 0; r < 8; r++) {
        const float* Br = Bs + r * 2048 + base;
        da += Tr[r] * Br[j0 + j];
        db += Tr[r] * Br[64 + j0 + j];
        de += Tr[r] * Br[2 * (j0 + j)];
        dd += Tr[r] * Br[2 * (j0 + j) + 1];
      }
      float qa = bf2f(qa4[j]) + da;
      float qb = bf2f(qb4[j]) + db;
      float qe = bf2f(qeo[2 * j]) + de;
      float qo = bf2f(qeo[2 * j + 1]) + dd;
      float c = ((const float*)&cv)[j], s = ((const float*)&sv)[j];
      o1[j] = (qa * c - qo * s) * qs;
      o2[j] = (qb * c + qe * s) * qs;
    }
    short4v w1, w2;
    #pragma unroll
    for (int j = 0; j < 4; j++) { w1[j] = f2bf(o1[j]); w2[j] = f2bf(o2[j]); }
    *(short4v*)(row + base + j0) = w1;        // safe: global reads were pass-1 only
    *(short4v*)(row + base + 64 + j0) = w2;
  }
}

// ---------------- V transpose: vT[bh][d][t] = qkv[b*2048+t][4096 + h*128 + d] ----------------
__global__ void k_vt(const short* __restrict__ qkv, short* __restrict__ vT) {
  __shared__ short tile[32][33];
  int bh = blockIdx.z, b = bh >> 4, h = bh & 15;
  int t0 = blockIdx.x * 32, d0 = blockIdx.y * 32;
  int tx = threadIdx.x, ty = threadIdx.y;  // (32,8)
  #pragma unroll
  for (int i = 0; i < 4; i++) {
    int tt = t0 + ty + i * 8;
    tile[ty + i * 8][tx] = qkv[(size_t)(b * 2048 + tt) * 6144 + 4096 + h * 128 + d0 + tx];
  }
  __syncthreads();
  #pragma unroll
  for (int i = 0; i < 4; i++) {
    int d = d0 + ty + i * 8;
    vT[((size_t)bh * 128 + d) * 2048 + t0 + tx] = tile[tx][ty + i * 8];
  }
}

// ---------------- causal flash attention v8.1 ----------------
// r12/r14/r17 proven structure + r22 wave-skip: on the last kv-tile
// (kt == 2*qt+1), waves 0-1 own q-rows qt*128+0..63 while all keys are
// qt*128+64..127 (strictly future) -> P==0, contributes nothing to o/ls.
// The compute section has NO block barrier, so those waves skip it wave-
// locally; staging + barriers unchanged.  launch_bounds(256,2) ONLY.
// K/V LDS staging REQUIRED (r15).
__global__ __launch_bounds__(256, 2) void k_attn(
    const short* __restrict__ qkv, const short* __restrict__ vT, short* __restrict__ y)
{
  __shared__ __attribute__((aligned(16))) short Ks[64 * 128];     // 16 KB, swz
  __shared__ __attribute__((aligned(16))) short Vs[128 * 64];     // 16 KB, swz
  __shared__ __attribute__((aligned(16))) short Ps[4 * 16 * 64];  // 8 KB, swz
  const int bh = blockIdx.x, b = bh >> 4, h = bh & 15;
  const int qt = 15 - (int)blockIdx.y;
  const int t = threadIdx.x, w = t >> 6, l = t & 63, g = l >> 4, c16 = l & 15;

  const int skr = t >> 2, sc0 = (t & 3) * 32;   // K staging: row, col base
  const int svd = t >> 1, sv0 = (t & 1) * 32;   // V staging
  const short* kbase = qkv + (size_t)(b * 2048) * 6144 + 2048 + h * 128;
  const short* vbase = vT + (size_t)bh * 128 * 2048;
  short* Pw = Ps + w * (16 * 64);

  short8 onesv;
  #pragma unroll
  for (int e = 0; e < 8; e++) onesv[e] = (short)0x3F80;  // bf16 1.0

  // Q A-fragments: wave w rows qt*128 + w*32 + m*16 + c16
  short8 qf[2][4];
  #pragma unroll
  for (int m = 0; m < 2; m++) {
    size_t goff = (size_t)(b * 2048 + qt * 128 + w * 32 + m * 16 + c16) * 6144 + h * 128;
    #pragma unroll
    for (int kf = 0; kf < 4; kf++)
      qf[m][kf] = *(const short8*)(qkv + goff + kf * 32 + 8 * g);
  }

  floatx4 o[2][8], ls[2];
  float mrow[2][4];
  #pragma unroll
  for (int m = 0; m < 2; m++) {
    #pragma unroll
    for (int nf = 0; nf < 8; nf++) o[m][nf] = (floatx4){0.f, 0.f, 0.f, 0.f};
    ls[m] = (floatx4){0.f, 0.f, 0.f, 0.f};
    #pragma unroll
    for (int r = 0; r < 4; r++) mrow[m][r] = -1e30f;
  }

  const int ntiles = 2 * qt + 2;

  // prologue: issue tile-0 loads into regs
  short8 kreg[4], vreg[4];
  #pragma unroll
  for (int ii = 0; ii < 4; ii++) {
    kreg[ii] = *(const short8*)(kbase + (size_t)skr * 6144 + sc0 + ii * 8);
    vreg[ii] = *(const short8*)(vbase + (size_t)svd * 2048 + sv0 + ii * 8);
  }

  for (int kt = 0; kt < ntiles; kt++) {
    __syncthreads();  // prior iter's LDS reads complete before overwrite
    #pragma unroll
    for (int ii = 0; ii < 4; ii++) {
      *(short8*)(Ks + SWZ(skr * 128 + sc0 + ii * 8, skr)) = kreg[ii];
      *(short8*)(Vs + SWZ(svd * 64 + sv0 + ii * 8, svd)) = vreg[ii];
    }
    __syncthreads();  // staged tile visible

    // T14: issue NEXT tile's global loads now; latency hides under compute.
    if (kt + 1 < ntiles) {
      #pragma unroll
      for (int ii = 0; ii < 4; ii++) {
        kreg[ii] = *(const short8*)(kbase + (size_t)((kt + 1) * 64 + skr) * 6144 + sc0 + ii * 8);
        vreg[ii] = *(const short8*)(vbase + (size_t)svd * 2048 + (kt + 1) * 64 + sv0 + ii * 8);
      }
    }

    // r22: waves 0-1 are fully masked on the last kv-tile -> skip (P==0).
    if (kt == 2 * qt + 1 && w < 2) continue;

    // ---- QK^T: sc[m][nf] over 64 keys (scores already in log2 units) ----
    floatx4 sc[2][4];
    #pragma unroll
    for (int m = 0; m < 2; m++)
      #pragma unroll
      for (int nf = 0; nf < 4; nf++) sc[m][nf] = (floatx4){0.f, 0.f, 0.f, 0.f};
    __builtin_amdgcn_s_setprio(1);
    #pragma unroll
    for (int kf = 0; kf < 4; kf++)
      #pragma unroll
      for (int nf = 0; nf < 4; nf++) {
        short8 kb = *(const short8*)(Ks + SWZ((nf * 16 + c16) * 128 + kf * 32 + 8 * g, c16));
        sc[0][nf] = __builtin_amdgcn_mfma_f32_16x16x32_bf16(qf[0][kf], kb, sc[0][nf], 0, 0, 0);
        sc[1][nf] = __builtin_amdgcn_mfma_f32_16x16x32_bf16(qf[1][kf], kb, sc[1][nf], 0, 0, 0);
      }
    __builtin_amdgcn_s_setprio(0);

    if (kt >= 2 * qt) {  // diagonal region: causal mask
      #pragma unroll
      for (int m = 0; m < 2; m++)
        #pragma unroll
        for (int nf = 0; nf < 4; nf++) {
          int key = kt * 64 + nf * 16 + c16;
          #pragma unroll
          for (int r = 0; r < 4; r++) {
            int qr = qt * 128 + w * 32 + m * 16 + g * 4 + r;
            if (key > qr) sc[m][nf][r] = -1e30f;
          }
        }
    }

    // ---- defer-max check: LANE-LOCAL (no cross-lane tree in common path) ----
    float need = -1e30f;
    #pragma unroll
    for (int m = 0; m < 2; m++)
      #pragma unroll
      for (int r = 0; r < 4; r++) {
        float rm = fmaxf(fmaxf(sc[m][0][r], sc[m][1][r]), fmaxf(sc[m][2][r], sc[m][3][r]));
        need = fmaxf(need, rm - mrow[m][r]);
      }
    if (!__all(need <= 11.0f)) {  // rare: full row-max tree + rescale
      #pragma unroll
      for (int m = 0; m < 2; m++) {
        #pragma unroll
        for (int r = 0; r < 4; r++) {
          float rm = fmaxf(fmaxf(sc[m][0][r], sc[m][1][r]), fmaxf(sc[m][2][r], sc[m][3][r]));
          rm = fmaxf(rm, __shfl_xor(rm, 1));
          rm = fmaxf(rm, __shfl_xor(rm, 2));
          rm = fmaxf(rm, __shfl_xor(rm, 4));
          rm = fmaxf(rm, __shfl_xor(rm, 8));
          float mn = fmaxf(mrow[m][r], rm);
          float al = EXP2F(mrow[m][r] - mn);
          mrow[m][r] = mn;
          ls[m][r] *= al;
          #pragma unroll
          for (int nf = 0; nf < 8; nf++) o[m][nf][r] *= al;
        }
      }
    }

    // ---- P + PV, two m-passes over the wave-private 2KB P region ----
    short8 pa[2][2];
    #pragma unroll
    for (int m = 0; m < 2; m++) {
      #pragma unroll
      for (int r = 0; r < 4; r++) {
        int prow = g * 4 + r;
        #pragma unroll
        for (int nf = 0; nf < 4; nf++) {
          float p = EXP2F(sc[m][nf][r] - mrow[m][r]);
          Pw[SWZ(prow * 64 + nf * 16 + c16, prow)] = f2bf_n(p);
        }
      }
      #pragma unroll
      for (int kf = 0; kf < 2; kf++)
        pa[m][kf] = *(const short8*)(Pw + SWZ(c16 * 64 + kf * 32 + 8 * g, c16));
      if (m == 0) {  // pa[0] data must be in regs before m=1 overwrites the region
        asm volatile("s_waitcnt lgkmcnt(0)" ::: "memory");
        __builtin_amdgcn_sched_barrier(0);
      }
    }
    __builtin_amdgcn_s_setprio(1);
    #pragma unroll
    for (int m = 0; m < 2; m++)
      #pragma unroll
      for (int kf = 0; kf < 2; kf++)
        ls[m] = __builtin_amdgcn_mfma_f32_16x16x32_bf16(pa[m][kf], onesv, ls[m], 0, 0, 0);
    #pragma unroll
    for (int kf = 0; kf < 2; kf++)
      #pragma unroll
      for (int nf = 0; nf < 8; nf++) {
        short8 vb = *(const short8*)(Vs + SWZ((nf * 16 + c16) * 64 + kf * 32 + 8 * g, c16));
        o[0][nf] = __builtin_amdgcn_mfma_f32_16x16x32_bf16(pa[0][kf], vb, o[0][nf], 0, 0, 0);
        o[1][nf] = __builtin_amdgcn_mfma_f32_16x16x32_bf16(pa[1][kf], vb, o[1][nf], 0, 0, 0);
      }
    __builtin_amdgcn_s_setprio(0);
  }

  #pragma unroll
  for (int m = 0; m < 2; m++) {
    float ri[4];
    #pragma unroll
    for (int r = 0; r < 4; r++) ri[r] = 1.0f / ls[m][r];
    size_t yr0 = (size_t)(b * 2048 + qt * 128 + w * 32 + m * 16 + g * 4);
    #pragma unroll
    for (int nf = 0; nf < 8; nf++) {
      int col = h * 128 + nf * 16 + c16;
      #pragma unroll
      for (int r = 0; r < 4; r++)
        y[(yr0 + r) * 2048 + col] = f2bf_n(o[m][nf][r] * ri[r]);
    }
  }
}

// ---------------------------------------------------------------------------
extern "C" void kernel_launch(void* const* d_in, const int* in_sizes, int n_in,
                              void* d_out, int out_size, void* d_ws, size_t ws_size,
                              hipStream_t stream) {
  (void)in_sizes; (void)n_in; (void)out_size; (void)ws_size;
  const float* x      = (const float*)d_in[0];
  const float* W_attn = (const float*)d_in[1];
  const float* b_attn = (const float*)d_in[2];
  const float* Aq     = (const float*)d_in[3];
  const float* Bq     = (const float*)d_in[4];
  const float* Ak     = (const float*)d_in[5];
  const float* Bk     = (const float*)d_in[6];
  const float* W_proj = (const float*)d_in[7];
  const float* b_proj = (const float*)d_in[8];

  char* ws = (char*)d_ws;
  short* xb  = (short*)(ws + 0);          // 8192x2048 bf16 (reused as y)
  short* WTa = (short*)(ws + 33554432);   // 6144x2048 bf16
  short* WTp = (short*)(ws + 58720256);   // 2048x2048 bf16
  short* qkv = (short*)(ws + 67108864);   // 8192x6144 bf16
  float* ct  = (float*)(ws + 168296448);  // 2048x64 f32
  float* st  = (float*)(ws + 168820736);
  short* vT  = (short*)(ws + 169345024);  // 64x128x2048 bf16  (end: 202899456)
  short* y   = xb;

  k_f2b<<<8192, 256, 0, stream>>>(x, xb, 2097152);
  k_wT<<<dim3(192, 64), dim3(32, 8), 0, stream>>>(W_attn, WTa, 2048, 6144);
  k_wT<<<dim3(64, 64), dim3(32, 8), 0, stream>>>(W_proj, WTp, 2048, 2048);
  k_ropetab<<<2048, 64, 0, stream>>>(ct, st);
  k_gemm8<short><<<dim3(32, 24), 512, 0, stream>>>(xb, WTa, b_attn, qkv, 8192, 6144, 2048);
  k_lorarope<<<dim3(512, 2), 256, 0, stream>>>(qkv, Aq, Ak, Bq, Bk, ct, st);
  k_vt<<<dim3(64, 4, 64), dim3(32, 8), 0, stream>>>(qkv, vT);
  k_attn<<<dim3(64, 16), 256, 0, stream>>>(qkv, vT, y);
  k_gemm8<float><<<dim3(32, 8), 512, 0, stream>>>(y, WTp, b_proj, (float*)d_out, 8192, 2048, 2048);
}